// Round 9
// baseline (332.104 us; speedup 1.0000x reference)
//
#include <hip/hip_runtime.h>

typedef __bf16 bf16;
typedef __bf16 bf16x4_t __attribute__((ext_vector_type(4)));
typedef __bf16 bf16x8_t __attribute__((ext_vector_type(8)));
typedef float  f32x4_t  __attribute__((ext_vector_type(4)));
typedef float  f32x16_t __attribute__((ext_vector_type(16)));
typedef unsigned int u32x4_t __attribute__((ext_vector_type(4)));

#define S_LEN 2048
#define NHEAD 16
#define NBH   64   // B*H

// async global->LDS, 16B per lane, linear dest (wave-uniform base + lane*16)
static __device__ __forceinline__ void glds16(const void* g, void* l) {
  __builtin_amdgcn_global_load_lds(
      (const __attribute__((address_space(1))) unsigned int*)g,
      (__attribute__((address_space(3))) unsigned int*)l, 16, 0, 0);
}

static __device__ __forceinline__ unsigned pk2(float lo, float hi) {
  unsigned short a = __builtin_bit_cast(unsigned short, (bf16)lo);
  unsigned short b = __builtin_bit_cast(unsigned short, (bf16)hi);
  return (unsigned)a | ((unsigned)b << 16);
}

// ---------------- f32 -> bf16 converts ----------------
__global__ __launch_bounds__(256) void cvt_x_kernel(const float4* __restrict__ in,
                                                    bf16x4_t* __restrict__ out) {
  int i = blockIdx.x * 256 + threadIdx.x;   // exactly 2097152 threads
  float4 v = in[i];
  bf16x4_t o = { (bf16)v.x, (bf16)v.y, (bf16)v.z, (bf16)v.w };
  out[i] = o;
}

__global__ __launch_bounds__(256) void cvt_w_kernel(const float* __restrict__ w0, const float* __restrict__ w1,
                                                    const float* __restrict__ w2, const float* __restrict__ w3,
                                                    bf16x4_t* __restrict__ out) {
  int i = blockIdx.x * 256 + threadIdx.x;   // exactly 1048576 threads (4 x 262144 float4)
  int sel = i >> 18;
  int j = i & 262143;
  const float4* src = (const float4*)(sel == 0 ? w0 : sel == 1 ? w1 : sel == 2 ? w2 : w3);
  float4 v = src[j];
  bf16x4_t o = { (bf16)v.x, (bf16)v.y, (bf16)v.z, (bf16)v.w };
  out[i] = o;
}

// ---------------- GEMM: C = A @ W^T (+bias), both operands K-major ----------------
// MODE 0: A = x_bf; W = {Wq,Wk,Wv} by blockIdx.z. z<2 -> fused RoPE, out per-head q/k (BH,S,64);
//         z==2 -> v transposed (BH,64,S), bf16
// MODE 1: A = o_ws bf16, W = Wo; out -> d_out f32 + bias
template<int MODE>
__global__ __launch_bounds__(256) void gemm_bt_kernel(
    const bf16* __restrict__ A, const bf16* __restrict__ Wb,
    const float* __restrict__ bias0, const float* __restrict__ bias1, const float* __restrict__ bias2,
    bf16* __restrict__ q_ws, bf16* __restrict__ k_ws, bf16* __restrict__ v_t,
    float* __restrict__ dout)
{
  __shared__ __align__(16) bf16 As[128 * 32];
  __shared__ __align__(16) bf16 Bs[128 * 32];
  const int tid  = threadIdx.x;
  const int lane = tid & 63, wid = tid >> 6;
  const int ql = lane & 15, lg = lane >> 4;
  const int wm = wid >> 1, wn = wid & 1;
  const int bm = blockIdx.x, bn = blockIdx.y;
  const int z  = (MODE == 0) ? blockIdx.z : 0;

  const bf16* Ag = A  + (long)bm * 128 * 1024;
  const bf16* Bg = Wb + (long)z * 1024 * 1024 + (long)bn * 128 * 1024;

  f32x4_t acc[4][4];
  const f32x4_t zero4 = { 0.f, 0.f, 0.f, 0.f };
  #pragma unroll
  for (int i = 0; i < 4; i++)
    #pragma unroll
    for (int j = 0; j < 4; j++) acc[i][j] = zero4;

  for (int k0 = 0; k0 < 1024; k0 += 32) {
    __syncthreads();                       // previous tile's ds_reads done
    #pragma unroll
    for (int r = 0; r < 2; r++) {
      int tt = tid + r * 256;
      int row = tt >> 2, kc = (tt & 3) * 8;
      glds16(Ag + (long)row * 1024 + k0 + kc, (void*)&As[tt * 8]);
    }
    #pragma unroll
    for (int r = 0; r < 2; r++) {
      int tt = tid + r * 256;
      int row = tt >> 2, kc = (tt & 3) * 8;
      glds16(Bg + (long)row * 1024 + k0 + kc, (void*)&Bs[tt * 8]);
    }
    __syncthreads();                       // compiler drains vmcnt before barrier

    bf16x8_t af[4], bf_[4];
    #pragma unroll
    for (int m = 0; m < 4; m++) af[m]  = *(const bf16x8_t*)&As[(wm * 64 + m * 16 + ql) * 32 + lg * 8];
    #pragma unroll
    for (int n = 0; n < 4; n++) bf_[n] = *(const bf16x8_t*)&Bs[(wn * 64 + n * 16 + ql) * 32 + lg * 8];
    #pragma unroll
    for (int m = 0; m < 4; m++)
      #pragma unroll
      for (int n = 0; n < 4; n++)
        acc[m][n] = __builtin_amdgcn_mfma_f32_16x16x32_bf16(af[m], bf_[n], acc[m][n], 0, 0, 0);
  }

  // epilogue: C/D layout col=lane&15, row=(lane>>4)*4+reg  [m89/m91]
  if (MODE == 1) {
    #pragma unroll
    for (int m = 0; m < 4; m++) {
      int rb = bm * 128 + wm * 64 + m * 16 + lg * 4;
      #pragma unroll
      for (int n = 0; n < 4; n++) {
        int colg = bn * 128 + wn * 64 + n * 16 + ql;
        float bb = bias0[colg];
        #pragma unroll
        for (int r = 0; r < 4; r++)
          dout[(long)(rb + r) * 1024 + colg] = acc[m][n][r] + bb;
      }
    }
  } else if (z == 2) {
    #pragma unroll
    for (int m = 0; m < 4; m++) {
      int rb = bm * 128 + wm * 64 + m * 16 + lg * 4;     // global token row (mult of 4)
      int bb_ = rb >> 11;                                 // batch
      int s0  = rb & 2047;                                // seq pos of reg 0
      #pragma unroll
      for (int n = 0; n < 4; n++) {
        int colg = bn * 128 + wn * 64 + n * 16 + ql;
        int h = colg >> 6, d = colg & 63;
        float bb = bias2[colg];
        // v transposed: v_t[(bh*64 + d)*2048 + s]; regs = 4 consecutive s -> 8B store
        ushort4 pkt;
        pkt.x = __builtin_bit_cast(unsigned short, (bf16)(acc[m][n][0] + bb));
        pkt.y = __builtin_bit_cast(unsigned short, (bf16)(acc[m][n][1] + bb));
        pkt.z = __builtin_bit_cast(unsigned short, (bf16)(acc[m][n][2] + bb));
        pkt.w = __builtin_bit_cast(unsigned short, (bf16)(acc[m][n][3] + bb));
        *(ushort4*)&v_t[((long)(bb_ * NHEAD + h) * 64 + d) * S_LEN + s0] = pkt;
      }
    }
  } else {
    // q or k with FUSED RoPE. For fixed (m,r) this thread holds cols d=n*16+ql (n=0..3)
    // of ONE head => pairs (n, n+2) are exactly (d, d+32) — rotate in-register.
    const float* bias = z ? bias1 : bias0;
    bf16* dst = z ? k_ws : q_ws;
    #pragma unroll
    for (int m = 0; m < 4; m++) {
      int rb = bm * 128 + wm * 64 + m * 16 + lg * 4;
      int bb_ = rb >> 11;
      int s0  = rb & 2047;
      #pragma unroll
      for (int n = 0; n < 2; n++) {
        int colg = bn * 128 + wn * 64 + n * 16 + ql;
        int h = colg >> 6, d = colg & 63;                 // d in [0,32)
        float b1 = bias[colg], b2 = bias[colg + 32];
        // inv_freq = 10000^(-d/32) = exp2(-d * log2(10000)/32)
        float inv = exp2f((float)d * -0.41524101186092026f);
        #pragma unroll
        for (int r = 0; r < 4; r++) {
          int s = s0 + r;
          float ang = (float)s * inv;
          float sn, cs;
          __sincosf(ang, &sn, &cs);
          float x1 = acc[m][n][r] + b1;
          float x2 = acc[m][n + 2][r] + b2;
          long base = ((long)(bb_ * NHEAD + h) * S_LEN + s) * 64;
          dst[base + d]      = (bf16)(x1 * cs - x2 * sn);
          dst[base + d + 32] = (bf16)(x2 * cs + x1 * sn);
        }
      }
    }
  }
}

// ---------------- flash attention: 1 WAVE per 32-q tile, KVBLK = 64 (2 indep sub-blocks) ----------------
// Swapped QK^T with mfma_f32_32x32x16: S^T = K_tile(32k x 16d) . Q^T(16d x 32q).
// C/D layout (m74/m101): col = lane&31 (=q), row crow(r,hi) = (r&3)+8*(r>>2)+4*hi (=k local).
// PV uses the shared phi k-mapping (cancels between V A-op and P^T B-op) so the P^T
// fragment is pack(pv[0..15]) with ZERO cross-lane ops (verified round 5).
// Round 9: KVBLK=64 — two independent 32-k sub-blocks per iteration (2 indep QK MFMA
// chains + 2 indep exp2 batches + 2 indep PV streams) amortize the serial softmax
// bookkeeping (1 shfl-pair + 1 defer-check per 64 rows) and hide chain latency with ILP.
// Round 8 showed the kernel is chain-latency-bound (all pipes <12%, VALU halved with
// zero time delta). __launch_bounds__(64,3): ~170 VGPR cap for the wider live set.
__global__ __launch_bounds__(64, 3) void attn_kernel(const bf16* __restrict__ qw, const bf16* __restrict__ kw,
                                                     const bf16* __restrict__ vt, bf16* __restrict__ ow,
                                                     const int* __restrict__ lens)
{
  const int lane = threadIdx.x & 63;
  const int lq = lane & 31, hi = lane >> 5;
  const int bh = blockIdx.x, b = bh >> 4, h = bh & 15;   // x fastest => all bh of a tile together
  const int len = lens[b];
  const int tile = 63 - (int)blockIdx.y;                 // longest causal tiles dispatch first
  const int q0 = tile * 32;
  const int qg = q0 + lq;

  const bf16* qh = qw + (long)bh * S_LEN * 64;
  const bf16* kh = kw + (long)bh * S_LEN * 64;
  const bf16* vh = vt + (long)bh * 64 * S_LEN;
  bf16* obase = ow + ((long)b * S_LEN + qg) * 1024 + h * 64;

  if (q0 >= len) {   // fully masked tile -> zero rows (proj then yields bo)
    ushort4 zz; zz.x = zz.y = zz.z = zz.w = 0;
    #pragma unroll
    for (int dblk = 0; dblk < 2; dblk++)
      #pragma unroll
      for (int g = 0; g < 4; g++)
        *(ushort4*)&obase[dblk * 32 + g * 8 + hi * 4] = zz;
    return;
  }

  // Q^T B-frags: lane holds q=lq col, d = ds*16 + hi*8 + j (16B contiguous loads).
  bf16x8_t qf[4];
  #pragma unroll
  for (int ds = 0; ds < 4; ds++)
    qf[ds] = *(const bf16x8_t*)&qh[(long)qg * 64 + ds * 16 + hi * 8];

  f32x16_t o0, o1;   // O^T accum, dblk 0/1: row d = dblk*32 + crow(r,hi), col q
  #pragma unroll
  for (int r = 0; r < 16; r++) { o0[r] = 0.f; o1[r] = 0.f; }

  // log2-domain: m_run tracks max of s*SCL; pv = exp2(fma(s, SCL, -m_run))
  const float SCL = 0.125f * 1.44269504088896f;
  const float THR = 11.5415603f;                // 8 ln-units in log2 (defer-max, T13)
  float m_run = -1e30f, l_run = 0.f;
  const int kend = min(q0 + 31, len - 1);

  // K prefetch for first 64-block: sub-block A rows lq, B rows 32+lq
  bf16x8_t kfA[4], kfB[4];
  #pragma unroll
  for (int ds = 0; ds < 4; ds++) {
    kfA[ds] = *(const bf16x8_t*)&kh[(long)lq * 64 + ds * 16 + hi * 8];
    kfB[ds] = *(const bf16x8_t*)&kh[(long)(32 + lq) * 64 + ds * 16 + hi * 8];
  }

  for (int k0 = 0; k0 <= kend; k0 += 64) {
    // V fragments for BOTH sub-blocks, phi-mapping:
    // element j <- V^T[d][kbase + ks*16 + 4*hi + (j&3) + 8*(j>>2)]  (issued first, consumed last)
    u32x4_t vwA[2][2], vwB[2][2];
    #pragma unroll
    for (int dblk = 0; dblk < 2; dblk++)
      #pragma unroll
      for (int ks = 0; ks < 2; ks++) {
        const bf16* va = &vh[(long)(dblk * 32 + lq) * S_LEN + k0 + ks * 16 + 4 * hi];
        uint2 a0 = *(const uint2*)(va);
        uint2 a1 = *(const uint2*)(va + 8);
        vwA[dblk][ks].x = a0.x; vwA[dblk][ks].y = a0.y;
        vwA[dblk][ks].z = a1.x; vwA[dblk][ks].w = a1.y;
        const bf16* vb = va + 32;
        uint2 b0 = *(const uint2*)(vb);
        uint2 b1 = *(const uint2*)(vb + 8);
        vwB[dblk][ks].x = b0.x; vwB[dblk][ks].y = b0.y;
        vwB[dblk][ks].z = b1.x; vwB[dblk][ks].w = b1.y;
      }

    // two INDEPENDENT S^T chains
    f32x16_t sA, sB;
    #pragma unroll
    for (int r = 0; r < 16; r++) { sA[r] = 0.f; sB[r] = 0.f; }
    #pragma unroll
    for (int ds = 0; ds < 4; ds++) {
      sA = __builtin_amdgcn_mfma_f32_32x32x16_bf16(kfA[ds], qf[ds], sA, 0, 0, 0);
      sB = __builtin_amdgcn_mfma_f32_32x32x16_bf16(kfB[ds], qf[ds], sB, 0, 0, 0);
    }

    // prefetch next 64-block's K (wave-uniform branch)
    if (k0 + 64 <= kend) {
      #pragma unroll
      for (int ds = 0; ds < 4; ds++) {
        kfA[ds] = *(const bf16x8_t*)&kh[(long)(k0 + 64 + lq) * 64 + ds * 16 + hi * 8];
        kfB[ds] = *(const bf16x8_t*)&kh[(long)(k0 + 96 + lq) * 64 + ds * 16 + hi * 8];
      }
    }

    // masking only on boundary blocks (wave-uniform test); interior skips it all.
    // interior: worst lane qg=q0 must cover kg=k0+63, and whole block < len.
    if (!(k0 + 63 <= q0 && k0 + 64 <= len)) {
      #pragma unroll
      for (int r = 0; r < 16; r++) {
        int crow = (r & 3) + 8 * (r >> 2) + 4 * hi;
        int kgA = k0 + crow, kgB = k0 + 32 + crow;
        sA[r] = (kgA <= qg && kgA < len) ? sA[r] : -3.0e38f;
        sB[r] = (kgB <= qg && kgB < len) ? sB[r] : -3.0e38f;
      }
    }

    // combined lane-local max over 32 values + one pair exchange
    float mx = fmaxf(sA[0], sB[0]);
    #pragma unroll
    for (int r = 1; r < 16; r++) mx = fmaxf(mx, fmaxf(sA[r], sB[r]));
    mx = fmaxf(mx, __shfl_xor(mx, 32));
    float mxl = mx * SCL;

    // defer-max (T13): only rescale when some q-column's max grew past THR
    if (__any(mxl > m_run + THR)) {
      float m_new = fmaxf(m_run, mxl);
      float sc = __builtin_amdgcn_exp2f(m_run - m_new);
      l_run *= sc;
      #pragma unroll
      for (int r = 0; r < 16; r++) { o0[r] *= sc; o1[r] *= sc; }
      m_run = m_new;
    }

    // two independent exp2 batches
    float pvA[16], pvB[16];
    float ps = 0.f;
    #pragma unroll
    for (int r = 0; r < 16; r++) {
      pvA[r] = __builtin_amdgcn_exp2f(__builtin_fmaf(sA[r], SCL, -m_run));
      pvB[r] = __builtin_amdgcn_exp2f(__builtin_fmaf(sB[r], SCL, -m_run));
      ps += pvA[r] + pvB[r];
    }
    ps += __shfl_xor(ps, 32);
    l_run += ps;

    // P^T B-frags under phi (per sub-block): pf*0 = pv[0..7], pf*1 = pv[8..15]
    u32x4_t fA0, fA1, fB0, fB1;
    fA0.x = pk2(pvA[0],  pvA[1]);  fA0.y = pk2(pvA[2],  pvA[3]);
    fA0.z = pk2(pvA[4],  pvA[5]);  fA0.w = pk2(pvA[6],  pvA[7]);
    fA1.x = pk2(pvA[8],  pvA[9]);  fA1.y = pk2(pvA[10], pvA[11]);
    fA1.z = pk2(pvA[12], pvA[13]); fA1.w = pk2(pvA[14], pvA[15]);
    fB0.x = pk2(pvB[0],  pvB[1]);  fB0.y = pk2(pvB[2],  pvB[3]);
    fB0.z = pk2(pvB[4],  pvB[5]);  fB0.w = pk2(pvB[6],  pvB[7]);
    fB1.x = pk2(pvB[8],  pvB[9]);  fB1.y = pk2(pvB[10], pvB[11]);
    fB1.z = pk2(pvB[12], pvB[13]); fB1.w = pk2(pvB[14], pvB[15]);
    bf16x8_t pfA0 = __builtin_bit_cast(bf16x8_t, fA0);
    bf16x8_t pfA1 = __builtin_bit_cast(bf16x8_t, fA1);
    bf16x8_t pfB0 = __builtin_bit_cast(bf16x8_t, fB0);
    bf16x8_t pfB1 = __builtin_bit_cast(bf16x8_t, fB1);

    // O^T += V^T . P^T for both sub-blocks (o0/o1 chains interleave A and B)
    o0 = __builtin_amdgcn_mfma_f32_32x32x16_bf16(__builtin_bit_cast(bf16x8_t, vwA[0][0]), pfA0, o0, 0, 0, 0);
    o1 = __builtin_amdgcn_mfma_f32_32x32x16_bf16(__builtin_bit_cast(bf16x8_t, vwA[1][0]), pfA0, o1, 0, 0, 0);
    o0 = __builtin_amdgcn_mfma_f32_32x32x16_bf16(__builtin_bit_cast(bf16x8_t, vwA[0][1]), pfA1, o0, 0, 0, 0);
    o1 = __builtin_amdgcn_mfma_f32_32x32x16_bf16(__builtin_bit_cast(bf16x8_t, vwA[1][1]), pfA1, o1, 0, 0, 0);
    o0 = __builtin_amdgcn_mfma_f32_32x32x16_bf16(__builtin_bit_cast(bf16x8_t, vwB[0][0]), pfB0, o0, 0, 0, 0);
    o1 = __builtin_amdgcn_mfma_f32_32x32x16_bf16(__builtin_bit_cast(bf16x8_t, vwB[1][0]), pfB0, o1, 0, 0, 0);
    o0 = __builtin_amdgcn_mfma_f32_32x32x16_bf16(__builtin_bit_cast(bf16x8_t, vwB[0][1]), pfB1, o0, 0, 0, 0);
    o1 = __builtin_amdgcn_mfma_f32_32x32x16_bf16(__builtin_bit_cast(bf16x8_t, vwB[1][1]), pfB1, o1, 0, 0, 0);
  }

  float rinv = (qg < len) ? (1.0f / l_run) : 0.f;  // masked rows -> exact 0
  #pragma unroll
  for (int g = 0; g < 4; g++) {
    ushort4 p0, p1;
    p0.x = __builtin_bit_cast(unsigned short, (bf16)(o0[4 * g + 0] * rinv));
    p0.y = __builtin_bit_cast(unsigned short, (bf16)(o0[4 * g + 1] * rinv));
    p0.z = __builtin_bit_cast(unsigned short, (bf16)(o0[4 * g + 2] * rinv));
    p0.w = __builtin_bit_cast(unsigned short, (bf16)(o0[4 * g + 3] * rinv));
    p1.x = __builtin_bit_cast(unsigned short, (bf16)(o1[4 * g + 0] * rinv));
    p1.y = __builtin_bit_cast(unsigned short, (bf16)(o1[4 * g + 1] * rinv));
    p1.z = __builtin_bit_cast(unsigned short, (bf16)(o1[4 * g + 2] * rinv));
    p1.w = __builtin_bit_cast(unsigned short, (bf16)(o1[4 * g + 3] * rinv));
    *(ushort4*)&obase[g * 8 + hi * 4]      = p0;
    *(ushort4*)&obase[32 + g * 8 + hi * 4] = p1;
  }
}

// ---------------- launch ----------------
extern "C" void kernel_launch(void* const* d_in, const int* in_sizes, int n_in,
                              void* d_out, int out_size, void* d_ws, size_t ws_size,
                              hipStream_t stream)
{
  const float* X  = (const float*)d_in[0];
  const float* Wq = (const float*)d_in[1];
  const float* bq = (const float*)d_in[2];
  const float* Wk = (const float*)d_in[3];
  const float* bk = (const float*)d_in[4];
  const float* Wv = (const float*)d_in[5];
  const float* bv = (const float*)d_in[6];
  const float* Wo = (const float*)d_in[7];
  const float* bo = (const float*)d_in[8];
  const int* lens = (const int*)d_in[9];
  float* out = (float*)d_out;

  char* ws = (char*)d_ws;
  bf16* x_bf = (bf16*)(ws);                         // 16 MiB: X as bf16 (8192 x 1024)
  bf16* w_bf = (bf16*)(ws + (16u << 20));           //  8 MiB: Wq,Wk,Wv,Wo bf16
  bf16* q_ws = (bf16*)(ws + (24u << 20));           // 16 MiB: (BH,S,64)
  bf16* k_ws = (bf16*)(ws + (40u << 20));           // 16 MiB: (BH,S,64)
  bf16* v_t  = (bf16*)(ws + (56u << 20));           // 16 MiB: (BH,64,S)
  bf16* o_ws = (bf16*)(ws + (72u << 20));           // 16 MiB: (B*S, 1024)

  cvt_x_kernel<<<8192, 256, 0, stream>>>((const float4*)X, (bf16x4_t*)x_bf);
  cvt_w_kernel<<<4096, 256, 0, stream>>>(Wq, Wk, Wv, Wo, (bf16x4_t*)w_bf);
  gemm_bt_kernel<0><<<dim3(64, 8, 3), 256, 0, stream>>>(x_bf, w_bf, bq, bk, bv,
                                                        q_ws, k_ws, v_t, nullptr);
  attn_kernel<<<dim3(NBH, 64), 64, 0, stream>>>(q_ws, k_ws, v_t, o_ws, lens);
  gemm_bt_kernel<1><<<dim3(64, 8, 1), 256, 0, stream>>>(o_ws, w_bf + 3u * 1048576u, bo, bo, bo,
                                                        q_ws, k_ws, v_t, out);
}

// Round 10
// 240.137 us; speedup vs baseline: 1.3830x; 1.3830x over previous
//
#include <hip/hip_runtime.h>

typedef __bf16 bf16;
typedef __bf16 bf16x4_t __attribute__((ext_vector_type(4)));
typedef __bf16 bf16x8_t __attribute__((ext_vector_type(8)));
typedef float  f32x4_t  __attribute__((ext_vector_type(4)));
typedef float  f32x16_t __attribute__((ext_vector_type(16)));
typedef unsigned int u32x4_t __attribute__((ext_vector_type(4)));

#define S_LEN 2048
#define NHEAD 16
#define NBH   64   // B*H

// async global->LDS, 16B per lane, linear dest (wave-uniform base + lane*16)
static __device__ __forceinline__ void glds16(const void* g, void* l) {
  __builtin_amdgcn_global_load_lds(
      (const __attribute__((address_space(1))) unsigned int*)g,
      (__attribute__((address_space(3))) unsigned int*)l, 16, 0, 0);
}

static __device__ __forceinline__ unsigned pk2(float lo, float hi) {
  unsigned short a = __builtin_bit_cast(unsigned short, (bf16)lo);
  unsigned short b = __builtin_bit_cast(unsigned short, (bf16)hi);
  return (unsigned)a | ((unsigned)b << 16);
}

// ---------------- f32 -> bf16 converts ----------------
__global__ __launch_bounds__(256) void cvt_x_kernel(const float4* __restrict__ in,
                                                    bf16x4_t* __restrict__ out) {
  int i = blockIdx.x * 256 + threadIdx.x;   // exactly 2097152 threads
  float4 v = in[i];
  bf16x4_t o = { (bf16)v.x, (bf16)v.y, (bf16)v.z, (bf16)v.w };
  out[i] = o;
}

__global__ __launch_bounds__(256) void cvt_w_kernel(const float* __restrict__ w0, const float* __restrict__ w1,
                                                    const float* __restrict__ w2, const float* __restrict__ w3,
                                                    bf16x4_t* __restrict__ out) {
  int i = blockIdx.x * 256 + threadIdx.x;   // exactly 1048576 threads (4 x 262144 float4)
  int sel = i >> 18;
  int j = i & 262143;
  const float4* src = (const float4*)(sel == 0 ? w0 : sel == 1 ? w1 : sel == 2 ? w2 : w3);
  float4 v = src[j];
  bf16x4_t o = { (bf16)v.x, (bf16)v.y, (bf16)v.z, (bf16)v.w };
  out[i] = o;
}

// ---------------- GEMM: C = A @ W^T (+bias), both operands K-major ----------------
// MODE 0: A = x_bf; W = {Wq,Wk,Wv} by blockIdx.z.
//   z==0 -> fused RoPE, q row-major (BH,S,64)
//   z==1 -> fused RoPE, k in MFMA-FRAGMENT layout kfrag[bh][k/32][ds][lane][j]
//           element = K[kb*32+lq][ds*16+hi*8+j], lane = hi*32+lq   (coalesced attn loads)
//   z==2 -> v in MFMA-FRAGMENT layout vfrag[bh][k/16][dblk][lane][j]
//           element = V^T[dblk*32+lq][kc*16 + 4*hi + (j&3) + 8*(j>>2)]  (phi-mapping)
// MODE 1: A = o_ws bf16, W = Wo; out -> d_out f32 + bias
template<int MODE>
__global__ __launch_bounds__(256) void gemm_bt_kernel(
    const bf16* __restrict__ A, const bf16* __restrict__ Wb,
    const float* __restrict__ bias0, const float* __restrict__ bias1, const float* __restrict__ bias2,
    bf16* __restrict__ q_ws, bf16* __restrict__ k_ws, bf16* __restrict__ v_t,
    float* __restrict__ dout)
{
  __shared__ __align__(16) bf16 As[128 * 32];
  __shared__ __align__(16) bf16 Bs[128 * 32];
  const int tid  = threadIdx.x;
  const int lane = tid & 63, wid = tid >> 6;
  const int ql = lane & 15, lg = lane >> 4;
  const int wm = wid >> 1, wn = wid & 1;
  const int bm = blockIdx.x, bn = blockIdx.y;
  const int z  = (MODE == 0) ? blockIdx.z : 0;

  const bf16* Ag = A  + (long)bm * 128 * 1024;
  const bf16* Bg = Wb + (long)z * 1024 * 1024 + (long)bn * 128 * 1024;

  f32x4_t acc[4][4];
  const f32x4_t zero4 = { 0.f, 0.f, 0.f, 0.f };
  #pragma unroll
  for (int i = 0; i < 4; i++)
    #pragma unroll
    for (int j = 0; j < 4; j++) acc[i][j] = zero4;

  for (int k0 = 0; k0 < 1024; k0 += 32) {
    __syncthreads();                       // previous tile's ds_reads done
    #pragma unroll
    for (int r = 0; r < 2; r++) {
      int tt = tid + r * 256;
      int row = tt >> 2, kc = (tt & 3) * 8;
      glds16(Ag + (long)row * 1024 + k0 + kc, (void*)&As[tt * 8]);
    }
    #pragma unroll
    for (int r = 0; r < 2; r++) {
      int tt = tid + r * 256;
      int row = tt >> 2, kc = (tt & 3) * 8;
      glds16(Bg + (long)row * 1024 + k0 + kc, (void*)&Bs[tt * 8]);
    }
    __syncthreads();                       // compiler drains vmcnt before barrier

    bf16x8_t af[4], bf_[4];
    #pragma unroll
    for (int m = 0; m < 4; m++) af[m]  = *(const bf16x8_t*)&As[(wm * 64 + m * 16 + ql) * 32 + lg * 8];
    #pragma unroll
    for (int n = 0; n < 4; n++) bf_[n] = *(const bf16x8_t*)&Bs[(wn * 64 + n * 16 + ql) * 32 + lg * 8];
    #pragma unroll
    for (int m = 0; m < 4; m++)
      #pragma unroll
      for (int n = 0; n < 4; n++)
        acc[m][n] = __builtin_amdgcn_mfma_f32_16x16x32_bf16(af[m], bf_[n], acc[m][n], 0, 0, 0);
  }

  // epilogue: C/D layout col=lane&15, row=(lane>>4)*4+reg  [m89/m91]
  if (MODE == 1) {
    #pragma unroll
    for (int m = 0; m < 4; m++) {
      int rb = bm * 128 + wm * 64 + m * 16 + lg * 4;
      #pragma unroll
      for (int n = 0; n < 4; n++) {
        int colg = bn * 128 + wn * 64 + n * 16 + ql;
        float bb = bias0[colg];
        #pragma unroll
        for (int r = 0; r < 4; r++)
          dout[(long)(rb + r) * 1024 + colg] = acc[m][n][r] + bb;
      }
    }
  } else if (z == 2) {
    // v -> fragment layout vfrag[bh][kc][dblk][lane][j]; this thread's 4 regs (r=0..3)
    // are tokens s0..s0+3 => j = 4*(c>>1)+r with c=(s0&15)>>2, hi=c&1 (consecutive j -> 8B store)
    #pragma unroll
    for (int m = 0; m < 4; m++) {
      int rb = bm * 128 + wm * 64 + m * 16 + lg * 4;     // token row (mult of 4)
      int bb_ = rb >> 11;                                 // batch
      int s0  = rb & 2047;
      int kc  = s0 >> 4;
      int c   = (s0 >> 2) & 3;
      int hi_ = c & 1, b2_ = c >> 1;
      #pragma unroll
      for (int n = 0; n < 4; n++) {
        int colg = bn * 128 + wn * 64 + n * 16 + ql;
        int h = colg >> 6, d = colg & 63;
        float bb = bias2[colg];
        int dblk = d >> 5, lq_ = d & 31;
        long idx = ((((long)(bb_ * NHEAD + h) * 128 + kc) * 2 + dblk) * 64 + hi_ * 32 + lq_) * 8 + 4 * b2_;
        ushort4 pkt;
        pkt.x = __builtin_bit_cast(unsigned short, (bf16)(acc[m][n][0] + bb));
        pkt.y = __builtin_bit_cast(unsigned short, (bf16)(acc[m][n][1] + bb));
        pkt.z = __builtin_bit_cast(unsigned short, (bf16)(acc[m][n][2] + bb));
        pkt.w = __builtin_bit_cast(unsigned short, (bf16)(acc[m][n][3] + bb));
        *(ushort4*)&v_t[idx] = pkt;
      }
    }
  } else if (z == 1) {
    // k with fused RoPE -> fragment layout kfrag[bh][kb][ds][lane][j]
    // element = K[kb*32+lq][ds*16+hi*8+j]; for dim dd: ds=dd>>4, hi=(dd>>3)&1, j=dd&7
    #pragma unroll
    for (int m = 0; m < 4; m++) {
      int rb = bm * 128 + wm * 64 + m * 16 + lg * 4;
      int bb_ = rb >> 11;
      int s0  = rb & 2047;
      #pragma unroll
      for (int n = 0; n < 2; n++) {
        int colg = bn * 128 + wn * 64 + n * 16 + ql;
        int h = colg >> 6, d = colg & 63;                 // d in [0,32)
        float b1 = bias1[colg], b2 = bias1[colg + 32];
        float inv = exp2f((float)d * -0.41524101186092026f);
        int ds_ = d >> 4, hi_ = (d >> 3) & 1, j_ = d & 7; // dim d; dim d+32 -> ds_+2, same hi,j
        long base_bh = (long)(bb_ * NHEAD + h) * 64;
        #pragma unroll
        for (int r = 0; r < 4; r++) {
          int s = s0 + r;
          float ang = (float)s * inv;
          float sn, cs;
          __sincosf(ang, &sn, &cs);
          float x1 = acc[m][n][r] + b1;
          float x2 = acc[m][n + 2][r] + b2;
          int kb = s >> 5, lq_ = s & 31;
          long lbase = ((base_bh + kb) * 4 + ds_) * 64 + hi_ * 32 + lq_;
          k_ws[lbase * 8 + j_]       = (bf16)(x1 * cs - x2 * sn);
          k_ws[(lbase + 128) * 8 + j_] = (bf16)(x2 * cs + x1 * sn);   // ds_+2 => +2*64 lanes
        }
      }
    }
  } else {
    // q with fused RoPE, row-major (loaded once per attn wave -> layout uncritical)
    #pragma unroll
    for (int m = 0; m < 4; m++) {
      int rb = bm * 128 + wm * 64 + m * 16 + lg * 4;
      int bb_ = rb >> 11;
      int s0  = rb & 2047;
      #pragma unroll
      for (int n = 0; n < 2; n++) {
        int colg = bn * 128 + wn * 64 + n * 16 + ql;
        int h = colg >> 6, d = colg & 63;                 // d in [0,32)
        float b1 = bias0[colg], b2 = bias0[colg + 32];
        float inv = exp2f((float)d * -0.41524101186092026f);
        #pragma unroll
        for (int r = 0; r < 4; r++) {
          int s = s0 + r;
          float ang = (float)s * inv;
          float sn, cs;
          __sincosf(ang, &sn, &cs);
          float x1 = acc[m][n][r] + b1;
          float x2 = acc[m][n + 2][r] + b2;
          long base = ((long)(bb_ * NHEAD + h) * S_LEN + s) * 64;
          q_ws[base + d]      = (bf16)(x1 * cs - x2 * sn);
          q_ws[base + d + 32] = (bf16)(x2 * cs + x1 * sn);
        }
      }
    }
  }
}

// ---------------- flash attention: 1 WAVE per 32-q tile (64-thread blocks), KVBLK = 32 ----------------
// Swapped QK^T with mfma_f32_32x32x16: S^T = K_tile(32k x 16d) . Q^T(16d x 32q).
// C/D layout (m74/m101): col = lane&31 (=q), row crow(r,hi) = (r&3)+8*(r>>2)+4*hi (=k local).
// PV uses the shared phi k-mapping (cancels between V A-op and P^T B-op) -> P^T frag =
// pack(pv[0..15]), zero cross-lane ops (verified rounds 5-9).
// Round 10: K and V are read from FRAGMENT-LAYOUT buffers written by the QKV GEMM -> every
// K/V load is base + lane*16B (fully coalesced, 16 cache lines per instruction instead of
// 32-64). Rounds 6-9 falsified VALU/ILP/locality theories; the remaining consistent model
// is TA/TCP transaction-throughput bound on scattered per-lane gathers (~1200 lines/iter).
// Per-lane fragment CONTENTS are identical to round 8 -> compute math unchanged.
__global__ __launch_bounds__(64, 4) void attn_kernel(const bf16* __restrict__ qw, const bf16* __restrict__ kfr_,
                                                     const bf16* __restrict__ vfr_, bf16* __restrict__ ow,
                                                     const int* __restrict__ lens)
{
  const int lane = threadIdx.x & 63;
  const int lq = lane & 31, hi = lane >> 5;
  const int bh = blockIdx.x, b = bh >> 4, h = bh & 15;   // x fastest => all bh of a tile together
  const int len = lens[b];
  const int tile = 63 - (int)blockIdx.y;                 // longest causal tiles dispatch first
  const int q0 = tile * 32;
  const int qg = q0 + lq;

  const bf16* qh  = qw   + (long)bh * S_LEN * 64;
  const bf16* kfr = kfr_ + (long)bh * (64 * 4 * 64 * 8);   // [kb][ds][lane][8]
  const bf16* vfr = vfr_ + (long)bh * (128 * 2 * 64 * 8);  // [kc][dblk][lane][8]
  bf16* obase = ow + ((long)b * S_LEN + qg) * 1024 + h * 64;

  if (q0 >= len) {   // fully masked tile -> zero rows (proj then yields bo)
    ushort4 zz; zz.x = zz.y = zz.z = zz.w = 0;
    #pragma unroll
    for (int dblk = 0; dblk < 2; dblk++)
      #pragma unroll
      for (int g = 0; g < 4; g++)
        *(ushort4*)&obase[dblk * 32 + g * 8 + hi * 4] = zz;
    return;
  }

  // Q^T B-frags: lane holds q=lq col, d = ds*16 + hi*8 + j (once per wave; layout uncritical)
  bf16x8_t qf[4];
  #pragma unroll
  for (int ds = 0; ds < 4; ds++)
    qf[ds] = *(const bf16x8_t*)&qh[(long)qg * 64 + ds * 16 + hi * 8];

  f32x16_t o0, o1;   // O^T accum, dblk 0/1: row d = dblk*32 + crow(r,hi), col q
  #pragma unroll
  for (int r = 0; r < 16; r++) { o0[r] = 0.f; o1[r] = 0.f; }

  // log2-domain: m_run tracks max of s*SCL; pv = exp2(fma(s, SCL, -m_run))
  const float SCL = 0.125f * 1.44269504088896f;
  const float THR = 11.5415603f;                // 8 ln-units in log2 (defer-max, T13)
  float m_run = -1e30f, l_run = 0.f;
  const int kend = min(q0 + 31, len - 1);

  // K prefetch for kb=0: coalesced fragment loads (lane*16B)
  bf16x8_t kf[4];
  #pragma unroll
  for (int ds = 0; ds < 4; ds++)
    kf[ds] = *(const bf16x8_t*)&kfr[((long)ds * 64 + lane) * 8];

  for (int k0 = 0; k0 <= kend; k0 += 32) {
    const int kc = k0 >> 4;
    // V fragments, coalesced: vfr[((kc+ks)*2 + dblk)*64 + lane] (issued first, consumed last)
    bf16x8_t vw[2][2];
    #pragma unroll
    for (int dblk = 0; dblk < 2; dblk++)
      #pragma unroll
      for (int ks = 0; ks < 2; ks++)
        vw[dblk][ks] = *(const bf16x8_t*)&vfr[(((long)(kc + ks) * 2 + dblk) * 64 + lane) * 8];

    // S^T = K . Q^T
    f32x16_t s;
    #pragma unroll
    for (int r = 0; r < 16; r++) s[r] = 0.f;
    #pragma unroll
    for (int ds = 0; ds < 4; ds++)
      s = __builtin_amdgcn_mfma_f32_32x32x16_bf16(kf[ds], qf[ds], s, 0, 0, 0);

    // prefetch next K tile (wave-uniform branch), coalesced
    if (k0 + 32 <= kend) {
      const long nb = (long)((k0 >> 5) + 1) * 4;
      #pragma unroll
      for (int ds = 0; ds < 4; ds++)
        kf[ds] = *(const bf16x8_t*)&kfr[((nb + ds) * 64 + lane) * 8];
    }

    // masking only on boundary iterations (wave-uniform test); interior skips it all
    if (!(k0 < q0 && k0 + 32 <= len)) {
      #pragma unroll
      for (int r = 0; r < 16; r++) {
        int kg = k0 + (r & 3) + 8 * (r >> 2) + 4 * hi;
        s[r] = (kg <= qg && kg < len) ? s[r] : -3.0e38f;
      }
    }

    // lane-local max + one pair exchange
    float mx = s[0];
    #pragma unroll
    for (int r = 1; r < 16; r++) mx = fmaxf(mx, s[r]);
    mx = fmaxf(mx, __shfl_xor(mx, 32));
    float mxl = mx * SCL;

    // defer-max (T13): only rescale when some q-column's max grew past THR
    if (__any(mxl > m_run + THR)) {
      float m_new = fmaxf(m_run, mxl);
      float sc = __builtin_amdgcn_exp2f(m_run - m_new);
      l_run *= sc;
      #pragma unroll
      for (int r = 0; r < 16; r++) { o0[r] *= sc; o1[r] *= sc; }
      m_run = m_new;
    }

    float pv[16];
    float ps = 0.f;
    #pragma unroll
    for (int r = 0; r < 16; r++) {
      pv[r] = __builtin_amdgcn_exp2f(__builtin_fmaf(s[r], SCL, -m_run));
      ps += pv[r];
    }
    ps += __shfl_xor(ps, 32);
    l_run += ps;

    // P^T B-frags under phi: pf0 = pv[0..7] (k local 0..15), pf1 = pv[8..15] (16..31)
    u32x4_t f0, f1;
    f0.x = pk2(pv[0],  pv[1]);  f0.y = pk2(pv[2],  pv[3]);
    f0.z = pk2(pv[4],  pv[5]);  f0.w = pk2(pv[6],  pv[7]);
    f1.x = pk2(pv[8],  pv[9]);  f1.y = pk2(pv[10], pv[11]);
    f1.z = pk2(pv[12], pv[13]); f1.w = pk2(pv[14], pv[15]);
    bf16x8_t pf0 = __builtin_bit_cast(bf16x8_t, f0);
    bf16x8_t pf1 = __builtin_bit_cast(bf16x8_t, f1);

    // O^T += V^T . P^T  (both operands share phi -> correct for any true HW k-layout)
    o0 = __builtin_amdgcn_mfma_f32_32x32x16_bf16(vw[0][0], pf0, o0, 0, 0, 0);
    o1 = __builtin_amdgcn_mfma_f32_32x32x16_bf16(vw[1][0], pf0, o1, 0, 0, 0);
    o0 = __builtin_amdgcn_mfma_f32_32x32x16_bf16(vw[0][1], pf1, o0, 0, 0, 0);
    o1 = __builtin_amdgcn_mfma_f32_32x32x16_bf16(vw[1][1], pf1, o1, 0, 0, 0);
  }

  float rinv = (qg < len) ? (1.0f / l_run) : 0.f;  // masked rows -> exact 0
  #pragma unroll
  for (int g = 0; g < 4; g++) {
    ushort4 p0, p1;
    p0.x = __builtin_bit_cast(unsigned short, (bf16)(o0[4 * g + 0] * rinv));
    p0.y = __builtin_bit_cast(unsigned short, (bf16)(o0[4 * g + 1] * rinv));
    p0.z = __builtin_bit_cast(unsigned short, (bf16)(o0[4 * g + 2] * rinv));
    p0.w = __builtin_bit_cast(unsigned short, (bf16)(o0[4 * g + 3] * rinv));
    p1.x = __builtin_bit_cast(unsigned short, (bf16)(o1[4 * g + 0] * rinv));
    p1.y = __builtin_bit_cast(unsigned short, (bf16)(o1[4 * g + 1] * rinv));
    p1.z = __builtin_bit_cast(unsigned short, (bf16)(o1[4 * g + 2] * rinv));
    p1.w = __builtin_bit_cast(unsigned short, (bf16)(o1[4 * g + 3] * rinv));
    *(ushort4*)&obase[g * 8 + hi * 4]      = p0;
    *(ushort4*)&obase[32 + g * 8 + hi * 4] = p1;
  }
}

// ---------------- launch ----------------
extern "C" void kernel_launch(void* const* d_in, const int* in_sizes, int n_in,
                              void* d_out, int out_size, void* d_ws, size_t ws_size,
                              hipStream_t stream)
{
  const float* X  = (const float*)d_in[0];
  const float* Wq = (const float*)d_in[1];
  const float* bq = (const float*)d_in[2];
  const float* Wk = (const float*)d_in[3];
  const float* bk = (const float*)d_in[4];
  const float* Wv = (const float*)d_in[5];
  const float* bv = (const float*)d_in[6];
  const float* Wo = (const float*)d_in[7];
  const float* bo = (const float*)d_in[8];
  const int* lens = (const int*)d_in[9];
  float* out = (float*)d_out;

  char* ws = (char*)d_ws;
  bf16* x_bf = (bf16*)(ws);                         // 16 MiB: X as bf16 (8192 x 1024)
  bf16* w_bf = (bf16*)(ws + (16u << 20));           //  8 MiB: Wq,Wk,Wv,Wo bf16
  bf16* q_ws = (bf16*)(ws + (24u << 20));           // 16 MiB: q row-major (BH,S,64)
  bf16* kfrag = (bf16*)(ws + (40u << 20));          // 16 MiB: k fragment layout
  bf16* vfrag = (bf16*)(ws + (56u << 20));          // 16 MiB: v fragment layout
  bf16* o_ws = (bf16*)(ws + (72u << 20));           // 16 MiB: (B*S, 1024)

  cvt_x_kernel<<<8192, 256, 0, stream>>>((const float4*)X, (bf16x4_t*)x_bf);
  cvt_w_kernel<<<4096, 256, 0, stream>>>(Wq, Wk, Wv, Wo, (bf16x4_t*)w_bf);
  gemm_bt_kernel<0><<<dim3(64, 8, 3), 256, 0, stream>>>(x_bf, w_bf, bq, bk, bv,
                                                        q_ws, kfrag, vfrag, nullptr);
  attn_kernel<<<dim3(NBH, 64), 64, 0, stream>>>(q_ws, kfrag, vfrag, o_ws, lens);
  gemm_bt_kernel<1><<<dim3(64, 8, 1), 256, 0, stream>>>(o_ws, w_bf + 3u * 1048576u, bo, bo, bo,
                                                        q_ws, kfrag, vfrag, out);
}

// Round 11
// 239.982 us; speedup vs baseline: 1.3839x; 1.0006x over previous
//
#include <hip/hip_runtime.h>

typedef __bf16 bf16;
typedef __bf16 bf16x4_t __attribute__((ext_vector_type(4)));
typedef __bf16 bf16x8_t __attribute__((ext_vector_type(8)));
typedef float  f32x4_t  __attribute__((ext_vector_type(4)));
typedef float  f32x16_t __attribute__((ext_vector_type(16)));
typedef unsigned int u32x4_t __attribute__((ext_vector_type(4)));

#define S_LEN 2048
#define NHEAD 16
#define NBH   64   // B*H

// async global->LDS, 16B per lane, linear dest (wave-uniform base + lane*16)
static __device__ __forceinline__ void glds16(const void* g, void* l) {
  __builtin_amdgcn_global_load_lds(
      (const __attribute__((address_space(1))) unsigned int*)g,
      (__attribute__((address_space(3))) unsigned int*)l, 16, 0, 0);
}

static __device__ __forceinline__ unsigned pk2(float lo, float hi) {
  unsigned short a = __builtin_bit_cast(unsigned short, (bf16)lo);
  unsigned short b = __builtin_bit_cast(unsigned short, (bf16)hi);
  return (unsigned)a | ((unsigned)b << 16);
}

// ---------------- f32 -> bf16 converts ----------------
__global__ __launch_bounds__(256) void cvt_x_kernel(const float4* __restrict__ in,
                                                    bf16x4_t* __restrict__ out) {
  int i = blockIdx.x * 256 + threadIdx.x;   // exactly 2097152 threads
  float4 v = in[i];
  bf16x4_t o = { (bf16)v.x, (bf16)v.y, (bf16)v.z, (bf16)v.w };
  out[i] = o;
}

__global__ __launch_bounds__(256) void cvt_w_kernel(const float* __restrict__ w0, const float* __restrict__ w1,
                                                    const float* __restrict__ w2, const float* __restrict__ w3,
                                                    bf16x4_t* __restrict__ out) {
  int i = blockIdx.x * 256 + threadIdx.x;   // exactly 1048576 threads (4 x 262144 float4)
  int sel = i >> 18;
  int j = i & 262143;
  const float4* src = (const float4*)(sel == 0 ? w0 : sel == 1 ? w1 : sel == 2 ? w2 : w3);
  float4 v = src[j];
  bf16x4_t o = { (bf16)v.x, (bf16)v.y, (bf16)v.z, (bf16)v.w };
  out[i] = o;
}

// ---------------- GEMM: C = A @ W^T (+bias), both operands K-major ----------------
// MODE 0: A = x_bf; W = {Wq,Wk,Wv} by blockIdx.z.
//   z==0 -> fused RoPE, q row-major (BH,S,64)
//   z==1 -> fused RoPE, k in MFMA-FRAGMENT layout kfrag[bh][k/32][ds][lane][j]
//           element = K[kb*32+lq][ds*16+hi*8+j], lane = hi*32+lq   (coalesced attn loads)
//   z==2 -> v in MFMA-FRAGMENT layout vfrag[bh][k/16][dblk][lane][j]
//           element = V^T[dblk*32+lq][kc*16 + 4*hi + (j&3) + 8*(j>>2)]  (phi-mapping)
// MODE 1: A = o_ws bf16, W = Wo; out -> d_out f32 + bias
template<int MODE>
__global__ __launch_bounds__(256) void gemm_bt_kernel(
    const bf16* __restrict__ A, const bf16* __restrict__ Wb,
    const float* __restrict__ bias0, const float* __restrict__ bias1, const float* __restrict__ bias2,
    bf16* __restrict__ q_ws, bf16* __restrict__ k_ws, bf16* __restrict__ v_t,
    float* __restrict__ dout)
{
  __shared__ __align__(16) bf16 As[128 * 32];
  __shared__ __align__(16) bf16 Bs[128 * 32];
  const int tid  = threadIdx.x;
  const int lane = tid & 63, wid = tid >> 6;
  const int ql = lane & 15, lg = lane >> 4;
  const int wm = wid >> 1, wn = wid & 1;
  const int bm = blockIdx.x, bn = blockIdx.y;
  const int z  = (MODE == 0) ? blockIdx.z : 0;

  const bf16* Ag = A  + (long)bm * 128 * 1024;
  const bf16* Bg = Wb + (long)z * 1024 * 1024 + (long)bn * 128 * 1024;

  f32x4_t acc[4][4];
  const f32x4_t zero4 = { 0.f, 0.f, 0.f, 0.f };
  #pragma unroll
  for (int i = 0; i < 4; i++)
    #pragma unroll
    for (int j = 0; j < 4; j++) acc[i][j] = zero4;

  for (int k0 = 0; k0 < 1024; k0 += 32) {
    __syncthreads();                       // previous tile's ds_reads done
    #pragma unroll
    for (int r = 0; r < 2; r++) {
      int tt = tid + r * 256;
      int row = tt >> 2, kc = (tt & 3) * 8;
      glds16(Ag + (long)row * 1024 + k0 + kc, (void*)&As[tt * 8]);
    }
    #pragma unroll
    for (int r = 0; r < 2; r++) {
      int tt = tid + r * 256;
      int row = tt >> 2, kc = (tt & 3) * 8;
      glds16(Bg + (long)row * 1024 + k0 + kc, (void*)&Bs[tt * 8]);
    }
    __syncthreads();                       // compiler drains vmcnt before barrier

    bf16x8_t af[4], bf_[4];
    #pragma unroll
    for (int m = 0; m < 4; m++) af[m]  = *(const bf16x8_t*)&As[(wm * 64 + m * 16 + ql) * 32 + lg * 8];
    #pragma unroll
    for (int n = 0; n < 4; n++) bf_[n] = *(const bf16x8_t*)&Bs[(wn * 64 + n * 16 + ql) * 32 + lg * 8];
    #pragma unroll
    for (int m = 0; m < 4; m++)
      #pragma unroll
      for (int n = 0; n < 4; n++)
        acc[m][n] = __builtin_amdgcn_mfma_f32_16x16x32_bf16(af[m], bf_[n], acc[m][n], 0, 0, 0);
  }

  // epilogue: C/D layout col=lane&15, row=(lane>>4)*4+reg  [m89/m91]
  if (MODE == 1) {
    #pragma unroll
    for (int m = 0; m < 4; m++) {
      int rb = bm * 128 + wm * 64 + m * 16 + lg * 4;
      #pragma unroll
      for (int n = 0; n < 4; n++) {
        int colg = bn * 128 + wn * 64 + n * 16 + ql;
        float bb = bias0[colg];
        #pragma unroll
        for (int r = 0; r < 4; r++)
          dout[(long)(rb + r) * 1024 + colg] = acc[m][n][r] + bb;
      }
    }
  } else if (z == 2) {
    // v -> fragment layout vfrag[bh][kc][dblk][lane][j]; this thread's 4 regs (r=0..3)
    // are tokens s0..s0+3 => j = 4*(c>>1)+r with c=(s0&15)>>2, hi=c&1 (consecutive j -> 8B store)
    #pragma unroll
    for (int m = 0; m < 4; m++) {
      int rb = bm * 128 + wm * 64 + m * 16 + lg * 4;     // token row (mult of 4)
      int bb_ = rb >> 11;                                 // batch
      int s0  = rb & 2047;
      int kc  = s0 >> 4;
      int c   = (s0 >> 2) & 3;
      int hi_ = c & 1, b2_ = c >> 1;
      #pragma unroll
      for (int n = 0; n < 4; n++) {
        int colg = bn * 128 + wn * 64 + n * 16 + ql;
        int h = colg >> 6, d = colg & 63;
        float bb = bias2[colg];
        int dblk = d >> 5, lq_ = d & 31;
        long idx = ((((long)(bb_ * NHEAD + h) * 128 + kc) * 2 + dblk) * 64 + hi_ * 32 + lq_) * 8 + 4 * b2_;
        ushort4 pkt;
        pkt.x = __builtin_bit_cast(unsigned short, (bf16)(acc[m][n][0] + bb));
        pkt.y = __builtin_bit_cast(unsigned short, (bf16)(acc[m][n][1] + bb));
        pkt.z = __builtin_bit_cast(unsigned short, (bf16)(acc[m][n][2] + bb));
        pkt.w = __builtin_bit_cast(unsigned short, (bf16)(acc[m][n][3] + bb));
        *(ushort4*)&v_t[idx] = pkt;
      }
    }
  } else if (z == 1) {
    // k with fused RoPE -> fragment layout kfrag[bh][kb][ds][lane][j]
    // element = K[kb*32+lq][ds*16+hi*8+j]; for dim dd: ds=dd>>4, hi=(dd>>3)&1, j=dd&7
    #pragma unroll
    for (int m = 0; m < 4; m++) {
      int rb = bm * 128 + wm * 64 + m * 16 + lg * 4;
      int bb_ = rb >> 11;
      int s0  = rb & 2047;
      #pragma unroll
      for (int n = 0; n < 2; n++) {
        int colg = bn * 128 + wn * 64 + n * 16 + ql;
        int h = colg >> 6, d = colg & 63;                 // d in [0,32)
        float b1 = bias1[colg], b2 = bias1[colg + 32];
        float inv = exp2f((float)d * -0.41524101186092026f);
        int ds_ = d >> 4, hi_ = (d >> 3) & 1, j_ = d & 7; // dim d; dim d+32 -> ds_+2, same hi,j
        long base_bh = (long)(bb_ * NHEAD + h) * 64;
        #pragma unroll
        for (int r = 0; r < 4; r++) {
          int s = s0 + r;
          float ang = (float)s * inv;
          float sn, cs;
          __sincosf(ang, &sn, &cs);
          float x1 = acc[m][n][r] + b1;
          float x2 = acc[m][n + 2][r] + b2;
          int kb = s >> 5, lq_ = s & 31;
          long lbase = ((base_bh + kb) * 4 + ds_) * 64 + hi_ * 32 + lq_;
          k_ws[lbase * 8 + j_]       = (bf16)(x1 * cs - x2 * sn);
          k_ws[(lbase + 128) * 8 + j_] = (bf16)(x2 * cs + x1 * sn);   // ds_+2 => +2*64 lanes
        }
      }
    }
  } else {
    // q with fused RoPE, row-major (loaded once per attn wave -> layout uncritical)
    #pragma unroll
    for (int m = 0; m < 4; m++) {
      int rb = bm * 128 + wm * 64 + m * 16 + lg * 4;
      int bb_ = rb >> 11;
      int s0  = rb & 2047;
      #pragma unroll
      for (int n = 0; n < 2; n++) {
        int colg = bn * 128 + wn * 64 + n * 16 + ql;
        int h = colg >> 6, d = colg & 63;                 // d in [0,32)
        float b1 = bias0[colg], b2 = bias0[colg + 32];
        float inv = exp2f((float)d * -0.41524101186092026f);
        #pragma unroll
        for (int r = 0; r < 4; r++) {
          int s = s0 + r;
          float ang = (float)s * inv;
          float sn, cs;
          __sincosf(ang, &sn, &cs);
          float x1 = acc[m][n][r] + b1;
          float x2 = acc[m][n + 2][r] + b2;
          long base = ((long)(bb_ * NHEAD + h) * S_LEN + s) * 64;
          q_ws[base + d]      = (bf16)(x1 * cs - x2 * sn);
          q_ws[base + d + 32] = (bf16)(x2 * cs + x1 * sn);
        }
      }
    }
  }
}

// ---------------- flash attention: 4-way SPLIT-K, 1 block (4 waves) per 32-q tile ----------------
// Swapped QK^T with mfma_f32_32x32x16: S^T = K_tile(32k x 16d) . Q^T(16d x 32q).
// C/D layout (m74/m101): col = lane&31 (=q), row crow(r,hi) = (r&3)+8*(r>>2)+4*hi (=k local).
// PV uses the shared phi k-mapping -> P^T frag = pack(pv[0..15]), zero cross-lane ops
// (verified rounds 5-10). K/V read from fragment-layout buffers (coalesced, r10 win).
// Round 11: wave w handles k-chunks {w, w+4, ...} with per-wave (m,l,o) state; waves 1-3
// publish partials to LDS (+1 pad, conflict-free), one barrier, wave 0 merges
// o = sum o_w * exp2(m_w - M) and stores. Critical path: 64 -> 16 chunks (r6-r9 showed
// wall-time == longest tile's serial chain; only splitting the k-range shortens it).
__global__ __launch_bounds__(256, 4) void attn_kernel(const bf16* __restrict__ qw, const bf16* __restrict__ kfr_,
                                                      const bf16* __restrict__ vfr_, bf16* __restrict__ ow,
                                                      const int* __restrict__ lens)
{
  const int tid = threadIdx.x;
  const int lane = tid & 63, wid = tid >> 6;
  const int lq = lane & 31, hi = lane >> 5;
  const int bh = blockIdx.x, b = bh >> 4, h = bh & 15;   // x fastest => all bh of a tile together
  const int len = lens[b];
  const int tile = 63 - (int)blockIdx.y;                 // longest causal tiles dispatch first
  const int q0 = tile * 32;
  const int qg = q0 + lq;

  __shared__ float sm_o[3][64][33];   // waves 1..3 partial O (o0[r]->[r], o1[r]->[16+r]); +1 pad
  __shared__ float sm_m[3][64];
  __shared__ float sm_l[3][64];

  const bf16* qh  = qw   + (long)bh * S_LEN * 64;
  const bf16* kfr = kfr_ + (long)bh * (64 * 4 * 64 * 8);   // [kb][ds][lane][8]
  const bf16* vfr = vfr_ + (long)bh * (128 * 2 * 64 * 8);  // [kc][dblk][lane][8]
  bf16* obase = ow + ((long)b * S_LEN + qg) * 1024 + h * 64;

  if (q0 >= len) {   // fully masked tile (block-uniform) -> wave 0 zeros rows, no barrier
    if (wid == 0) {
      ushort4 zz; zz.x = zz.y = zz.z = zz.w = 0;
      #pragma unroll
      for (int dblk = 0; dblk < 2; dblk++)
        #pragma unroll
        for (int g = 0; g < 4; g++)
          *(ushort4*)&obase[dblk * 32 + g * 8 + hi * 4] = zz;
    }
    return;
  }

  // Q^T B-frags: lane holds q=lq col, d = ds*16 + hi*8 + j (once per wave)
  bf16x8_t qf[4];
  #pragma unroll
  for (int ds = 0; ds < 4; ds++)
    qf[ds] = *(const bf16x8_t*)&qh[(long)qg * 64 + ds * 16 + hi * 8];

  f32x16_t o0, o1;   // O^T accum, dblk 0/1: row d = dblk*32 + crow(r,hi), col q
  #pragma unroll
  for (int r = 0; r < 16; r++) { o0[r] = 0.f; o1[r] = 0.f; }

  // log2-domain: m_run tracks max of s*SCL; pv = exp2(fma(s, SCL, -m_run))
  const float SCL = 0.125f * 1.44269504088896f;
  const float THR = 11.5415603f;                // 8 ln-units in log2 (defer-max, T13)
  float m_run = -1e30f, l_run = 0.f;
  const int kend = min(q0 + 31, len - 1);

  // K prefetch for this wave's first chunk (kb = wid; in-bounds even if unused)
  bf16x8_t kf[4];
  #pragma unroll
  for (int ds = 0; ds < 4; ds++)
    kf[ds] = *(const bf16x8_t*)&kfr[(((long)wid * 4 + ds) * 64 + lane) * 8];

  for (int k0 = wid * 32; k0 <= kend; k0 += 128) {
    const int kc = k0 >> 4;
    // V fragments, coalesced (issued first, consumed last)
    bf16x8_t vw[2][2];
    #pragma unroll
    for (int dblk = 0; dblk < 2; dblk++)
      #pragma unroll
      for (int ks = 0; ks < 2; ks++)
        vw[dblk][ks] = *(const bf16x8_t*)&vfr[(((long)(kc + ks) * 2 + dblk) * 64 + lane) * 8];

    // S^T = K . Q^T
    f32x16_t s;
    #pragma unroll
    for (int r = 0; r < 16; r++) s[r] = 0.f;
    #pragma unroll
    for (int ds = 0; ds < 4; ds++)
      s = __builtin_amdgcn_mfma_f32_32x32x16_bf16(kf[ds], qf[ds], s, 0, 0, 0);

    // prefetch this wave's next chunk (wave-uniform branch), coalesced
    if (k0 + 128 <= kend) {
      const long nb = (long)((k0 >> 5) + 4) * 4;
      #pragma unroll
      for (int ds = 0; ds < 4; ds++)
        kf[ds] = *(const bf16x8_t*)&kfr[((nb + ds) * 64 + lane) * 8];
    }

    // masking only on boundary chunks (wave-uniform test); interior skips it all
    if (!(k0 < q0 && k0 + 32 <= len)) {
      #pragma unroll
      for (int r = 0; r < 16; r++) {
        int kg = k0 + (r & 3) + 8 * (r >> 2) + 4 * hi;
        s[r] = (kg <= qg && kg < len) ? s[r] : -3.0e38f;
      }
    }

    // lane-local max + one pair exchange
    float mx = s[0];
    #pragma unroll
    for (int r = 1; r < 16; r++) mx = fmaxf(mx, s[r]);
    mx = fmaxf(mx, __shfl_xor(mx, 32));
    float mxl = mx * SCL;

    // defer-max (T13): only rescale when some q-column's max grew past THR
    if (__any(mxl > m_run + THR)) {
      float m_new = fmaxf(m_run, mxl);
      float sc = __builtin_amdgcn_exp2f(m_run - m_new);
      l_run *= sc;
      #pragma unroll
      for (int r = 0; r < 16; r++) { o0[r] *= sc; o1[r] *= sc; }
      m_run = m_new;
    }

    float pv[16];
    float ps = 0.f;
    #pragma unroll
    for (int r = 0; r < 16; r++) {
      pv[r] = __builtin_amdgcn_exp2f(__builtin_fmaf(s[r], SCL, -m_run));
      ps += pv[r];
    }
    ps += __shfl_xor(ps, 32);
    l_run += ps;

    // P^T B-frags under phi: pf0 = pv[0..7] (k local 0..15), pf1 = pv[8..15] (16..31)
    u32x4_t f0, f1;
    f0.x = pk2(pv[0],  pv[1]);  f0.y = pk2(pv[2],  pv[3]);
    f0.z = pk2(pv[4],  pv[5]);  f0.w = pk2(pv[6],  pv[7]);
    f1.x = pk2(pv[8],  pv[9]);  f1.y = pk2(pv[10], pv[11]);
    f1.z = pk2(pv[12], pv[13]); f1.w = pk2(pv[14], pv[15]);
    bf16x8_t pf0 = __builtin_bit_cast(bf16x8_t, f0);
    bf16x8_t pf1 = __builtin_bit_cast(bf16x8_t, f1);

    // O^T += V^T . P^T  (both operands share phi -> correct for any true HW k-layout)
    o0 = __builtin_amdgcn_mfma_f32_32x32x16_bf16(vw[0][0], pf0, o0, 0, 0, 0);
    o1 = __builtin_amdgcn_mfma_f32_32x32x16_bf16(vw[1][0], pf0, o1, 0, 0, 0);
    o0 = __builtin_amdgcn_mfma_f32_32x32x16_bf16(vw[0][1], pf1, o0, 0, 0, 0);
    o1 = __builtin_amdgcn_mfma_f32_32x32x16_bf16(vw[1][1], pf1, o1, 0, 0, 0);
  }

  // publish partials (waves 1-3), then wave 0 merges
  if (wid != 0) {
    #pragma unroll
    for (int r = 0; r < 16; r++) {
      sm_o[wid - 1][lane][r]      = o0[r];
      sm_o[wid - 1][lane][16 + r] = o1[r];
    }
    sm_m[wid - 1][lane] = m_run;
    sm_l[wid - 1][lane] = l_run;
  }
  __syncthreads();
  if (wid == 0) {
    float M = m_run;
    #pragma unroll
    for (int w = 0; w < 3; w++) M = fmaxf(M, sm_m[w][lane]);
    float sc0 = __builtin_amdgcn_exp2f(m_run - M);
    float lt = l_run * sc0;
    #pragma unroll
    for (int r = 0; r < 16; r++) { o0[r] *= sc0; o1[r] *= sc0; }
    #pragma unroll
    for (int w = 0; w < 3; w++) {
      float scw = __builtin_amdgcn_exp2f(sm_m[w][lane] - M);
      lt += sm_l[w][lane] * scw;
      #pragma unroll
      for (int r = 0; r < 16; r++) {
        o0[r] += sm_o[w][lane][r]      * scw;
        o1[r] += sm_o[w][lane][16 + r] * scw;
      }
    }
    float rinv = (qg < len) ? (1.0f / lt) : 0.f;  // masked rows -> exact 0
    #pragma unroll
    for (int g = 0; g < 4; g++) {
      ushort4 p0, p1;
      p0.x = __builtin_bit_cast(unsigned short, (bf16)(o0[4 * g + 0] * rinv));
      p0.y = __builtin_bit_cast(unsigned short, (bf16)(o0[4 * g + 1] * rinv));
      p0.z = __builtin_bit_cast(unsigned short, (bf16)(o0[4 * g + 2] * rinv));
      p0.w = __builtin_bit_cast(unsigned short, (bf16)(o0[4 * g + 3] * rinv));
      p1.x = __builtin_bit_cast(unsigned short, (bf16)(o1[4 * g + 0] * rinv));
      p1.y = __builtin_bit_cast(unsigned short, (bf16)(o1[4 * g + 1] * rinv));
      p1.z = __builtin_bit_cast(unsigned short, (bf16)(o1[4 * g + 2] * rinv));
      p1.w = __builtin_bit_cast(unsigned short, (bf16)(o1[4 * g + 3] * rinv));
      *(ushort4*)&obase[g * 8 + hi * 4]      = p0;
      *(ushort4*)&obase[32 + g * 8 + hi * 4] = p1;
    }
  }
}

// ---------------- launch ----------------
extern "C" void kernel_launch(void* const* d_in, const int* in_sizes, int n_in,
                              void* d_out, int out_size, void* d_ws, size_t ws_size,
                              hipStream_t stream)
{
  const float* X  = (const float*)d_in[0];
  const float* Wq = (const float*)d_in[1];
  const float* bq = (const float*)d_in[2];
  const float* Wk = (const float*)d_in[3];
  const float* bk = (const float*)d_in[4];
  const float* Wv = (const float*)d_in[5];
  const float* bv = (const float*)d_in[6];
  const float* Wo = (const float*)d_in[7];
  const float* bo = (const float*)d_in[8];
  const int* lens = (const int*)d_in[9];
  float* out = (float*)d_out;

  char* ws = (char*)d_ws;
  bf16* x_bf = (bf16*)(ws);                         // 16 MiB: X as bf16 (8192 x 1024)
  bf16* w_bf = (bf16*)(ws + (16u << 20));           //  8 MiB: Wq,Wk,Wv,Wo bf16
  bf16* q_ws = (bf16*)(ws + (24u << 20));           // 16 MiB: q row-major (BH,S,64)
  bf16* kfrag = (bf16*)(ws + (40u << 20));          // 16 MiB: k fragment layout
  bf16* vfrag = (bf16*)(ws + (56u << 20));          // 16 MiB: v fragment layout
  bf16* o_ws = (bf16*)(ws + (72u << 20));           // 16 MiB: (B*S, 1024)

  cvt_x_kernel<<<8192, 256, 0, stream>>>((const float4*)X, (bf16x4_t*)x_bf);
  cvt_w_kernel<<<4096, 256, 0, stream>>>(Wq, Wk, Wv, Wo, (bf16x4_t*)w_bf);
  gemm_bt_kernel<0><<<dim3(64, 8, 3), 256, 0, stream>>>(x_bf, w_bf, bq, bk, bv,
                                                        q_ws, kfrag, vfrag, nullptr);
  attn_kernel<<<dim3(NBH, 64), 256, 0, stream>>>(q_ws, kfrag, vfrag, o_ws, lens);
  gemm_bt_kernel<1><<<dim3(64, 8, 1), 256, 0, stream>>>(o_ws, w_bf + 3u * 1048576u, bo, bo, bo,
                                                        q_ws, kfrag, vfrag, out);
}